// Round 3
// baseline (254.413 us; speedup 1.0000x reference)
//
#include <hip/hip_runtime.h>

// Head: k = x@Wk^T; q = k (source bug); wei = softmax(causal(q k^T / 8)); v = x@Wv^T; out = wei@v
// B=8, T=2048, C=1024, H=64. fp32 in/out, bf16 MFMA internally.
//
// R8 -> R9: DIAGNOSTIC ROUND. R8's changes (attn setprio, proj direct-A) regressed
// +7us -> both reverted; source is R7 (best structure, 128.3us) verbatim EXCEPT
// attn_kernel is launched 9x (idempotent: reads only Kbuf/Vt, rewrites identical
// Opart/lpart). dur_us then yields T_attn = (dur - 128.3 - 8*gap)/8, giving the
// per-kernel visibility the top-5 counter table can't (all our kernels sit below
// the 41us workspace-poison fills). Decision rules precommitted in the journal.

typedef __bf16 bf16;
typedef __bf16 bf16x4 __attribute__((ext_vector_type(4)));
typedef __bf16 bf16x8 __attribute__((ext_vector_type(8)));
typedef float  floatx4 __attribute__((ext_vector_type(4)));

#define T_LEN 2048
#define HEAD  64
#define CEMB  1024

static __device__ __forceinline__ bf16x8 cvt2(float4 a, float4 b) {
    bf16x8 r;
    r[0] = (bf16)a.x; r[1] = (bf16)a.y; r[2] = (bf16)a.z; r[3] = (bf16)a.w;
    r[4] = (bf16)b.x; r[5] = (bf16)b.y; r[6] = (bf16)b.z; r[7] = (bf16)b.w;
    return r;
}

// async 16B global->LDS. LDS dest is wave-uniform base + lane*16 (linear);
// global src is per-lane. Completion tracked by vmcnt; __syncthreads drains it.
static __device__ __forceinline__ void gload_lds16(const void* g, void* l) {
    __builtin_amdgcn_global_load_lds(
        (const __attribute__((address_space(1))) unsigned int*)(unsigned long long)g,
        (__attribute__((address_space(3))) unsigned int*)(unsigned long long)l,
        16, 0, 0);
}

// ---------------- Kernel 0: W fp32 -> bf16, [Wk;Wv] concat as Wb[128][1024]
__global__ __launch_bounds__(256) void wconv_kernel(const float* __restrict__ Wk,
                                                    const float* __restrict__ Wv,
                                                    bf16* __restrict__ Wb) {
    int i = (blockIdx.x * 256 + threadIdx.x) * 4;   // grid 128 covers 131072
    const float* src = (i < 64 * 1024) ? (Wk + i) : (Wv + (i - 64 * 1024));
    float4 f = *(const float4*)src;
    bf16x4 v;
    v[0] = (bf16)f.x; v[1] = (bf16)f.y; v[2] = (bf16)f.z; v[3] = (bf16)f.w;
    *(bf16x4*)&Wb[i] = v;
}

// ---------------- Kernel 1: projection GEMM. grid 512, tile 32 rows x 128 cols, BK=64.
// A: fp32 register prefetch (depth-2) + cvt -> padded As. B: global_load_lds into
// swizzled Bs[2][128][64] (one barrier per K-step, DMA drained by it).
__global__ __launch_bounds__(256) void proj_kernel(const float* __restrict__ x,
                                                   const bf16* __restrict__ Wb,
                                                   bf16* __restrict__ Kbuf,
                                                   bf16* __restrict__ Vt) {
    __shared__ __align__(16) bf16 As[2][32][72];
    __shared__ __align__(16) bf16 Bs[2][128][64];   // linear rows (128B), XOR-swizzled cols

    const int tid  = threadIdx.x;
    const int wave = tid >> 6;
    const int lane = tid & 63;
    const int quad = lane >> 4;
    const int low  = lane & 15;

    const long row0 = (long)blockIdx.x * 32;

    const int a_row = tid >> 3;          // 0..31, 8 fp32/thread
    const int a_col = (tid & 7) * 8;
    const float* abase = x + (row0 + a_row) * CEMB + a_col;

    // B staging geometry: linear LDS offset o=(r*256+tid)*16 -> row=r*32+(tid>>3),
    // col byte cbp=(tid&7)*16. Source col = cbp ^ ((row&7)<<4) (pre-swizzle).
    const int brow = tid >> 3;
    const int cbp  = (tid & 7) * 16;
    const int bsw  = cbp ^ ((brow & 7) << 4);
    const char* bsrc0 = (const char*)Wb + (long)brow * (CEMB * 2) + bsw;  // +r*65536 +s*128
    char* bdst = (char*)&Bs[0][0][0] + wave * 1024;                       // +nb*16384 +r*4096

    const int strip = wave & 1;          // 16-row M strip
    const int nhalf = wave >> 1;         // 0 -> K n-tiles, 1 -> V n-tiles
    const int nq    = nhalf * 4;

    floatx4 acc[4];
#pragma unroll
    for (int i = 0; i < 4; ++i) acc[i] = (floatx4){0.f, 0.f, 0.f, 0.f};

    float4 apf[2][2];

    // prologue: A step0 -> regs -> LDS0; B step0 DMA -> Bs[0]; A step1 -> regs
    apf[0][0] = ((const float4*)abase)[0];
    apf[0][1] = ((const float4*)abase)[1];
#pragma unroll
    for (int r = 0; r < 4; ++r)
        gload_lds16(bsrc0 + (long)r * 65536, bdst + r * 4096);
    *(bf16x8*)&As[0][a_row][a_col] = cvt2(apf[0][0], apf[0][1]);
    apf[1][0] = ((const float4*)(abase + 64))[0];
    apf[1][1] = ((const float4*)(abase + 64))[1];
    __syncthreads();   // drains B(0) DMA

    const int bswz = (low & 7) << 4;
    int buf = 0;
    for (int s = 0; s < 16; ++s) {
        if (s < 15) {
            const int q  = (s + 1) & 1;
            const int nb = buf ^ 1;
            // A(s+1) regs -> LDS[nb]; B(s+1) DMA -> Bs[nb] (in flight during compute)
            *(bf16x8*)&As[nb][a_row][a_col] = cvt2(apf[q][0], apf[q][1]);
#pragma unroll
            for (int r = 0; r < 4; ++r)
                gload_lds16(bsrc0 + (long)r * 65536 + (s + 1) * 128,
                            bdst + nb * 16384 + r * 4096);
        }
        if (s < 14) {   // A(s+2) global -> regs: full-iteration latency cover
            const int q  = s & 1;
            const int k0 = (s + 2) * 64;
            apf[q][0] = ((const float4*)(abase + k0))[0];
            apf[q][1] = ((const float4*)(abase + k0))[1];
        }
        // compute current step
        const char* bsl = (const char*)&Bs[buf][0][0];
#pragma unroll
        for (int ks = 0; ks < 2; ++ks) {
            bf16x8 afrag = *(const bf16x8*)&As[buf][strip * 16 + low][ks * 32 + quad * 8];
            const int cb = (ks * 64 + quad * 16) ^ bswz;
#pragma unroll
            for (int i = 0; i < 4; ++i) {
                bf16x8 bfrag = *(const bf16x8*)(bsl + ((nq + i) * 16 + low) * 128 + cb);
                acc[i] = __builtin_amdgcn_mfma_f32_16x16x32_bf16(afrag, bfrag, acc[i], 0, 0, 0);
            }
        }
        if (s < 15) {
            __syncthreads();
            buf ^= 1;
        }
    }

    // epilogue via LDS transpose (alias retired Bs): coalesced 16B stores.
    __syncthreads();
    bf16* Ek = (bf16*)&Bs[0][0][0];   // [32][72]: Ek[t][h]
    bf16* Ev = (bf16*)&Bs[1][0][0];   // [64][36]: Ev[h][t]
    if (nhalf == 0) {
#pragma unroll
        for (int i = 0; i < 4; ++i)
#pragma unroll
            for (int r = 0; r < 4; ++r)
                Ek[(strip * 16 + quad * 4 + r) * 72 + i * 16 + low] = (bf16)acc[i][r];
    } else {
#pragma unroll
        for (int i = 0; i < 4; ++i)
#pragma unroll
            for (int r = 0; r < 4; ++r)
                Ev[(i * 16 + low) * 36 + strip * 16 + quad * 4 + r] = (bf16)acc[i][r];
    }
    __syncthreads();

    const long bidx  = row0 >> 11;
    const int  tloc0 = (int)(row0 & 2047);
    {   // K copy: 16B contiguous, fully coalesced
        const int t  = tid >> 3;
        const int h0 = (tid & 7) * 8;
        *(bf16x8*)&Kbuf[(bidx * T_LEN + tloc0 + t) * HEAD + h0] = *(const bf16x8*)&Ek[t * 72 + h0];
    }
    {   // V copy: 16B contiguous per h-row
        const int h  = tid >> 2;
        const int t0 = (tid & 3) * 8;
        *(bf16x8*)&Vt[(bidx * HEAD + h) * T_LEN + tloc0 + t0] = *(const bf16x8*)&Ev[h * 36 + t0];
    }
}

// ---------------- Kernel 2: attention partial. q=k, causal, scale 1/8, fixed-max softmax.
// blockIdx.x = ((b*32 + qb)*4 + c); chunk c: kv tiles j in {c, c+4, ...} <= qb (max 8 iters).
// K/V staged via global_load_lds into swizzled Ks/Vs[2][64][64]; 1 barrier/iter.
__global__ __launch_bounds__(256) void attn_kernel(const bf16* __restrict__ Kbuf,
                                                   const bf16* __restrict__ Vt,
                                                   bf16* __restrict__ Opart,
                                                   float* __restrict__ lpart) {
    __shared__ __align__(16) bf16 Ks[2][64][64];
    __shared__ __align__(16) bf16 Vs[2][64][64];   // [h][kv]
    __shared__ __align__(16) bf16 Ps[4][16][72];   // per-wave private

    const int tid  = threadIdx.x;
    const int wave = tid >> 6;
    const int lane = tid & 63;
    const int quad = lane >> 4;
    const int low  = lane & 15;

    const int c  = blockIdx.x & 3;
    const int qb = (blockIdx.x >> 2) & 31;
    const int b  = blockIdx.x >> 7;

    const bf16* kbase = Kbuf + (long)b * T_LEN * HEAD;
    const bf16* vbase = Vt + (long)b * HEAD * T_LEN;

    // Q fragments (A-layout) direct from global (once per block)
    const bf16* qrow = kbase + (qb * 64 + wave * 16 + low) * HEAD + quad * 8;
    const bf16x8 qf0 = *(const bf16x8*)(qrow);
    const bf16x8 qf1 = *(const bf16x8*)(qrow + 32);

    bf16x8 ones;
#pragma unroll
    for (int i = 0; i < 8; ++i) ones[i] = (bf16)1.0f;

    floatx4 o[4], ol;
#pragma unroll
    for (int nt = 0; nt < 4; ++nt) o[nt] = (floatx4){0.f, 0.f, 0.f, 0.f};
    ol = (floatx4){0.f, 0.f, 0.f, 0.f};

    // staging geometry: linear o=(r*256+tid)*16 -> row=r*32+(tid>>3), cbp=(tid&7)*16.
    const int srow = tid >> 3;
    const int cbp  = (tid & 7) * 16;
    const int ssw  = cbp ^ ((srow & 7) << 4);
    const char* ksrc0 = (const char*)kbase + (long)srow * 128  + ssw;  // +j*8192 +r*4096
    const char* vsrc0 = (const char*)vbase + (long)srow * 4096 + ssw;  // +j*128  +r*131072
    char* kdst = (char*)&Ks[0][0][0] + wave * 1024;
    char* vdst = (char*)&Vs[0][0][0] + wave * 1024;

    const int sw  = (low & 7) << 4;
    const int cb0 = (quad * 16) ^ sw;
    const int cb1 = (64 + quad * 16) ^ sw;

    if (c <= qb) {
        // prologue: stage tile j=c into buf 0
#pragma unroll
        for (int r = 0; r < 2; ++r) {
            gload_lds16(ksrc0 + (long)c * 8192 + r * 4096, kdst + r * 4096);
            gload_lds16(vsrc0 + (long)c * 128 + (long)r * 131072, vdst + r * 4096);
        }
        __syncthreads();

        int buf = 0;
        for (int j = c; j <= qb; j += 4) {
            const bool more = (j + 4 <= qb);
            if (more) {   // DMA next tile into alternate buffer, in flight during compute
                const int nb = buf ^ 1;
#pragma unroll
                for (int r = 0; r < 2; ++r) {
                    gload_lds16(ksrc0 + (long)(j + 4) * 8192 + r * 4096,
                                kdst + nb * 8192 + r * 4096);
                    gload_lds16(vsrc0 + (long)(j + 4) * 128 + (long)r * 131072,
                                vdst + nb * 8192 + r * 4096);
                }
            }
            const char* ksl = (const char*)&Ks[buf][0][0];
            const char* vsl = (const char*)&Vs[buf][0][0];

            // S = Q K^T ; per-wave S tile [16 x 64]
            floatx4 s_[4];
#pragma unroll
            for (int nt = 0; nt < 4; ++nt) {
                bf16x8 kf0 = *(const bf16x8*)(ksl + (nt * 16 + low) * 128 + cb0);
                bf16x8 kf1 = *(const bf16x8*)(ksl + (nt * 16 + low) * 128 + cb1);
                floatx4 z = (floatx4){0.f, 0.f, 0.f, 0.f};
                z = __builtin_amdgcn_mfma_f32_16x16x32_bf16(qf0, kf0, z, 0, 0, 0);
                z = __builtin_amdgcn_mfma_f32_16x16x32_bf16(qf1, kf1, z, 0, 0, 0);
                s_[nt] = z;
            }

            // p = exp2(s * 0.125*log2e); causal mask on diagonal tile; P strip -> LDS
            const bool diag = (j == qb);
#pragma unroll
            for (int nt = 0; nt < 4; ++nt) {
#pragma unroll
                for (int r = 0; r < 4; ++r) {
                    float p = __builtin_amdgcn_exp2f(s_[nt][r] * 0.180336880f);
                    if (diag && (nt * 16 + low) > (wave * 16 + quad * 4 + r)) p = 0.f;
                    Ps[wave][quad * 4 + r][nt * 16 + low] = (bf16)p;
                }
            }

            // O += P V ; l += P . ones  (Ps wave-private: lgkmcnt ordering suffices)
            bf16x8 pf0 = *(const bf16x8*)&Ps[wave][low][quad * 8];
            bf16x8 pf1 = *(const bf16x8*)&Ps[wave][low][32 + quad * 8];
#pragma unroll
            for (int nt = 0; nt < 4; ++nt) {
                bf16x8 vf0 = *(const bf16x8*)(vsl + (nt * 16 + low) * 128 + cb0);
                bf16x8 vf1 = *(const bf16x8*)(vsl + (nt * 16 + low) * 128 + cb1);
                o[nt] = __builtin_amdgcn_mfma_f32_16x16x32_bf16(pf0, vf0, o[nt], 0, 0, 0);
                o[nt] = __builtin_amdgcn_mfma_f32_16x16x32_bf16(pf1, vf1, o[nt], 0, 0, 0);
            }
            ol = __builtin_amdgcn_mfma_f32_16x16x32_bf16(pf0, ones, ol, 0, 0, 0);
            ol = __builtin_amdgcn_mfma_f32_16x16x32_bf16(pf1, ones, ol, 0, 0, 0);

            if (more) {   // barrier drains the DMA; swap buffers
                __syncthreads();
                buf ^= 1;
            }
        }
    }

    // epilogue via LDS transpose (alias retired Ks, 16KB >= 9.2KB): coalesced stores
    __syncthreads();
    bf16* Eo = (bf16*)&Ks[0][0][0];   // [64][72]: Eo[row][h]
#pragma unroll
    for (int nt = 0; nt < 4; ++nt)
#pragma unroll
        for (int r = 0; r < 4; ++r)
            Eo[(wave * 16 + quad * 4 + r) * 72 + nt * 16 + low] = (bf16)o[nt][r];
    __syncthreads();
    {
        const int row  = tid >> 2;
        const int col0 = (tid & 3) * 16;
        bf16* ob = Opart + (long)blockIdx.x * 4096 + row * 64 + col0;
        *(bf16x8*)(ob)     = *(const bf16x8*)&Eo[row * 72 + col0];
        *(bf16x8*)(ob + 8) = *(const bf16x8*)&Eo[row * 72 + col0 + 8];
    }
    if (low == 0) {
#pragma unroll
        for (int r = 0; r < 4; ++r)
            lpart[(long)blockIdx.x * 64 + wave * 16 + quad * 4 + r] = ol[r];
    }
}

// ---------------- Kernel 3: combine 4 chunks. out = sum_c Opart / sum_c lpart.
// grid 1024: 4 blocks per (b,qb) tile (16 rows each) for occupancy.
__global__ __launch_bounds__(256) void attn_combine(const bf16* __restrict__ Opart,
                                                    const float* __restrict__ lpart,
                                                    float* __restrict__ out) {
    const int tile = blockIdx.x >> 2;        // 0..255 = b*32+qb
    const int rg   = blockIdx.x & 3;
    const int tid  = threadIdx.x;
    const int row  = rg * 16 + (tid >> 4);   // 0..63
    const int col0 = (tid & 15) * 4;

    const bf16*  ob = Opart + (long)tile * 4 * 4096 + row * 64 + col0;
    const float* lb = lpart + (long)tile * 4 * 64 + row;

    float l = lb[0] + lb[64] + lb[128] + lb[192];
    float rl = 1.0f / l;

    float s[4] = {0.f, 0.f, 0.f, 0.f};
#pragma unroll
    for (int ch = 0; ch < 4; ++ch) {
        bf16x4 u = *(const bf16x4*)(ob + ch * 4096);
#pragma unroll
        for (int i = 0; i < 4; ++i) s[i] += (float)u[i];
    }
    float4 w;
    w.x = s[0] * rl; w.y = s[1] * rl; w.z = s[2] * rl; w.w = s[3] * rl;
    *(float4*)(out + (long)tile * 4096 + row * 64 + col0) = w;
}

extern "C" void kernel_launch(void* const* d_in, const int* in_sizes, int n_in,
                              void* d_out, int out_size, void* d_ws, size_t ws_size,
                              hipStream_t stream) {
    const float* x  = (const float*)d_in[0];
    const float* Wk = (const float*)d_in[1];
    const float* Wv = (const float*)d_in[2];
    float* out = (float*)d_out;

    char* ws = (char*)d_ws;
    bf16*  Wb    = (bf16*)ws;                           // 256 KB
    bf16*  Kbuf  = (bf16*)(ws + (1 << 20));             // 2 MB
    bf16*  Vt    = (bf16*)(ws + (3 << 20));             // 2 MB
    bf16*  Opart = (bf16*)(ws + (5 << 20));             // 8 MB
    float* lpart = (float*)(ws + (13 << 20));           // 256 KB

    wconv_kernel<<<128, 256, 0, stream>>>(Wk, Wv, Wb);
    proj_kernel<<<512, 256, 0, stream>>>(x, Wb, Kbuf, Vt);
    // DIAGNOSTIC: 9 idempotent attn launches -> T_attn = (dur - 128.3 - 8*gap)/8.
    for (int rep = 0; rep < 9; ++rep)
        attn_kernel<<<1024, 256, 0, stream>>>(Kbuf, Vt, Opart, lpart);
    attn_combine<<<1024, 256, 0, stream>>>(Opart, lpart, out);
}

// Round 4
// 205.962 us; speedup vs baseline: 1.2352x; 1.2352x over previous
//
#include <hip/hip_runtime.h>

// Head: k = x@Wk^T; q = k (source bug); wei = softmax(causal(q k^T / 8)); v = x@Wv^T; out = wei@v
// B=8, T=2048, C=1024, H=64. fp32 in/out, bf16 MFMA internally.
//
// R9 -> R10: DIAGNOSTIC ROUND 2. R9 pinned attn at ~15us incl. launch gap -> the ~95us
// residual must be proj (model says 12-15us: 6x disagreement) or harness-structural.
// proj grid is amplified 512 -> 4608 (replica = bid>>9 recomputes the same tile and
// writes identical bytes -> race-free); the single proj dispatch then exceeds the 41us
// poison fills and enters the top-5 counter table WITH FULL COUNTERS (MfmaUtil,
// VALUBusy, Occupancy, FETCH, bank conflicts) -- first per-kernel visibility of the
// session. Everything else is the banked-best R7 structure verbatim (1x attn).
// Decision rules precommitted in journal; de-amplify next round.

typedef __bf16 bf16;
typedef __bf16 bf16x4 __attribute__((ext_vector_type(4)));
typedef __bf16 bf16x8 __attribute__((ext_vector_type(8)));
typedef float  floatx4 __attribute__((ext_vector_type(4)));

#define T_LEN 2048
#define HEAD  64
#define CEMB  1024

static __device__ __forceinline__ bf16x8 cvt2(float4 a, float4 b) {
    bf16x8 r;
    r[0] = (bf16)a.x; r[1] = (bf16)a.y; r[2] = (bf16)a.z; r[3] = (bf16)a.w;
    r[4] = (bf16)b.x; r[5] = (bf16)b.y; r[6] = (bf16)b.z; r[7] = (bf16)b.w;
    return r;
}

// async 16B global->LDS. LDS dest is wave-uniform base + lane*16 (linear);
// global src is per-lane. Completion tracked by vmcnt; __syncthreads drains it.
static __device__ __forceinline__ void gload_lds16(const void* g, void* l) {
    __builtin_amdgcn_global_load_lds(
        (const __attribute__((address_space(1))) unsigned int*)(unsigned long long)g,
        (__attribute__((address_space(3))) unsigned int*)(unsigned long long)l,
        16, 0, 0);
}

// ---------------- Kernel 0: W fp32 -> bf16, [Wk;Wv] concat as Wb[128][1024]
__global__ __launch_bounds__(256) void wconv_kernel(const float* __restrict__ Wk,
                                                    const float* __restrict__ Wv,
                                                    bf16* __restrict__ Wb) {
    int i = (blockIdx.x * 256 + threadIdx.x) * 4;   // grid 128 covers 131072
    const float* src = (i < 64 * 1024) ? (Wk + i) : (Wv + (i - 64 * 1024));
    float4 f = *(const float4*)src;
    bf16x4 v;
    v[0] = (bf16)f.x; v[1] = (bf16)f.y; v[2] = (bf16)f.z; v[3] = (bf16)f.w;
    *(bf16x4*)&Wb[i] = v;
}

// ---------------- Kernel 1: projection GEMM. AMPLIFIED grid 4608 = 9 x 512 replicas
// (diagnostic; replicas write identical bytes). orig tile 32 rows x 128 cols, BK=64.
// A: fp32 register prefetch (depth-2) + cvt -> padded As. B: global_load_lds into
// swizzled Bs[2][128][64] (one barrier per K-step, DMA drained by it).
__global__ __launch_bounds__(256) void proj_kernel(const float* __restrict__ x,
                                                   const bf16* __restrict__ Wb,
                                                   bf16* __restrict__ Kbuf,
                                                   bf16* __restrict__ Vt) {
    __shared__ __align__(16) bf16 As[2][32][72];
    __shared__ __align__(16) bf16 Bs[2][128][64];   // linear rows (128B), XOR-swizzled cols

    const int tid  = threadIdx.x;
    const int wave = tid >> 6;
    const int lane = tid & 63;
    const int quad = lane >> 4;
    const int low  = lane & 15;

    // replica-minor: bid 0..511 = replica 0 (cache-cold, representative), etc.
    const long row0 = (long)(blockIdx.x & 511) * 32;

    const int a_row = tid >> 3;          // 0..31, 8 fp32/thread
    const int a_col = (tid & 7) * 8;
    const float* abase = x + (row0 + a_row) * CEMB + a_col;

    // B staging geometry: linear LDS offset o=(r*256+tid)*16 -> row=r*32+(tid>>3),
    // col byte cbp=(tid&7)*16. Source col = cbp ^ ((row&7)<<4) (pre-swizzle).
    const int brow = tid >> 3;
    const int cbp  = (tid & 7) * 16;
    const int bsw  = cbp ^ ((brow & 7) << 4);
    const char* bsrc0 = (const char*)Wb + (long)brow * (CEMB * 2) + bsw;  // +r*65536 +s*128
    char* bdst = (char*)&Bs[0][0][0] + wave * 1024;                       // +nb*16384 +r*4096

    const int strip = wave & 1;          // 16-row M strip
    const int nhalf = wave >> 1;         // 0 -> K n-tiles, 1 -> V n-tiles
    const int nq    = nhalf * 4;

    floatx4 acc[4];
#pragma unroll
    for (int i = 0; i < 4; ++i) acc[i] = (floatx4){0.f, 0.f, 0.f, 0.f};

    float4 apf[2][2];

    // prologue: A step0 -> regs -> LDS0; B step0 DMA -> Bs[0]; A step1 -> regs
    apf[0][0] = ((const float4*)abase)[0];
    apf[0][1] = ((const float4*)abase)[1];
#pragma unroll
    for (int r = 0; r < 4; ++r)
        gload_lds16(bsrc0 + (long)r * 65536, bdst + r * 4096);
    *(bf16x8*)&As[0][a_row][a_col] = cvt2(apf[0][0], apf[0][1]);
    apf[1][0] = ((const float4*)(abase + 64))[0];
    apf[1][1] = ((const float4*)(abase + 64))[1];
    __syncthreads();   // drains B(0) DMA

    const int bswz = (low & 7) << 4;
    int buf = 0;
    for (int s = 0; s < 16; ++s) {
        if (s < 15) {
            const int q  = (s + 1) & 1;
            const int nb = buf ^ 1;
            // A(s+1) regs -> LDS[nb]; B(s+1) DMA -> Bs[nb] (in flight during compute)
            *(bf16x8*)&As[nb][a_row][a_col] = cvt2(apf[q][0], apf[q][1]);
#pragma unroll
            for (int r = 0; r < 4; ++r)
                gload_lds16(bsrc0 + (long)r * 65536 + (s + 1) * 128,
                            bdst + nb * 16384 + r * 4096);
        }
        if (s < 14) {   // A(s+2) global -> regs: full-iteration latency cover
            const int q  = s & 1;
            const int k0 = (s + 2) * 64;
            apf[q][0] = ((const float4*)(abase + k0))[0];
            apf[q][1] = ((const float4*)(abase + k0))[1];
        }
        // compute current step
        const char* bsl = (const char*)&Bs[buf][0][0];
#pragma unroll
        for (int ks = 0; ks < 2; ++ks) {
            bf16x8 afrag = *(const bf16x8*)&As[buf][strip * 16 + low][ks * 32 + quad * 8];
            const int cb = (ks * 64 + quad * 16) ^ bswz;
#pragma unroll
            for (int i = 0; i < 4; ++i) {
                bf16x8 bfrag = *(const bf16x8*)(bsl + ((nq + i) * 16 + low) * 128 + cb);
                acc[i] = __builtin_amdgcn_mfma_f32_16x16x32_bf16(afrag, bfrag, acc[i], 0, 0, 0);
            }
        }
        if (s < 15) {
            __syncthreads();
            buf ^= 1;
        }
    }

    // epilogue via LDS transpose (alias retired Bs): coalesced 16B stores.
    __syncthreads();
    bf16* Ek = (bf16*)&Bs[0][0][0];   // [32][72]: Ek[t][h]
    bf16* Ev = (bf16*)&Bs[1][0][0];   // [64][36]: Ev[h][t]
    if (nhalf == 0) {
#pragma unroll
        for (int i = 0; i < 4; ++i)
#pragma unroll
            for (int r = 0; r < 4; ++r)
                Ek[(strip * 16 + quad * 4 + r) * 72 + i * 16 + low] = (bf16)acc[i][r];
    } else {
#pragma unroll
        for (int i = 0; i < 4; ++i)
#pragma unroll
            for (int r = 0; r < 4; ++r)
                Ev[(i * 16 + low) * 36 + strip * 16 + quad * 4 + r] = (bf16)acc[i][r];
    }
    __syncthreads();

    const long bidx  = row0 >> 11;
    const int  tloc0 = (int)(row0 & 2047);
    {   // K copy: 16B contiguous, fully coalesced
        const int t  = tid >> 3;
        const int h0 = (tid & 7) * 8;
        *(bf16x8*)&Kbuf[(bidx * T_LEN + tloc0 + t) * HEAD + h0] = *(const bf16x8*)&Ek[t * 72 + h0];
    }
    {   // V copy: 16B contiguous per h-row
        const int h  = tid >> 2;
        const int t0 = (tid & 3) * 8;
        *(bf16x8*)&Vt[(bidx * HEAD + h) * T_LEN + tloc0 + t0] = *(const bf16x8*)&Ev[h * 36 + t0];
    }
}

// ---------------- Kernel 2: attention partial. q=k, causal, scale 1/8, fixed-max softmax.
// blockIdx.x = ((b*32 + qb)*4 + c); chunk c: kv tiles j in {c, c+4, ...} <= qb (max 8 iters).
// K/V staged via global_load_lds into swizzled Ks/Vs[2][64][64]; 1 barrier/iter.
__global__ __launch_bounds__(256) void attn_kernel(const bf16* __restrict__ Kbuf,
                                                   const bf16* __restrict__ Vt,
                                                   bf16* __restrict__ Opart,
                                                   float* __restrict__ lpart) {
    __shared__ __align__(16) bf16 Ks[2][64][64];
    __shared__ __align__(16) bf16 Vs[2][64][64];   // [h][kv]
    __shared__ __align__(16) bf16 Ps[4][16][72];   // per-wave private

    const int tid  = threadIdx.x;
    const int wave = tid >> 6;
    const int lane = tid & 63;
    const int quad = lane >> 4;
    const int low  = lane & 15;

    const int c  = blockIdx.x & 3;
    const int qb = (blockIdx.x >> 2) & 31;
    const int b  = blockIdx.x >> 7;

    const bf16* kbase = Kbuf + (long)b * T_LEN * HEAD;
    const bf16* vbase = Vt + (long)b * HEAD * T_LEN;

    // Q fragments (A-layout) direct from global (once per block)
    const bf16* qrow = kbase + (qb * 64 + wave * 16 + low) * HEAD + quad * 8;
    const bf16x8 qf0 = *(const bf16x8*)(qrow);
    const bf16x8 qf1 = *(const bf16x8*)(qrow + 32);

    bf16x8 ones;
#pragma unroll
    for (int i = 0; i < 8; ++i) ones[i] = (bf16)1.0f;

    floatx4 o[4], ol;
#pragma unroll
    for (int nt = 0; nt < 4; ++nt) o[nt] = (floatx4){0.f, 0.f, 0.f, 0.f};
    ol = (floatx4){0.f, 0.f, 0.f, 0.f};

    // staging geometry: linear o=(r*256+tid)*16 -> row=r*32+(tid>>3), cbp=(tid&7)*16.
    const int srow = tid >> 3;
    const int cbp  = (tid & 7) * 16;
    const int ssw  = cbp ^ ((srow & 7) << 4);
    const char* ksrc0 = (const char*)kbase + (long)srow * 128  + ssw;  // +j*8192 +r*4096
    const char* vsrc0 = (const char*)vbase + (long)srow * 4096 + ssw;  // +j*128  +r*131072
    char* kdst = (char*)&Ks[0][0][0] + wave * 1024;
    char* vdst = (char*)&Vs[0][0][0] + wave * 1024;

    const int sw  = (low & 7) << 4;
    const int cb0 = (quad * 16) ^ sw;
    const int cb1 = (64 + quad * 16) ^ sw;

    if (c <= qb) {
        // prologue: stage tile j=c into buf 0
#pragma unroll
        for (int r = 0; r < 2; ++r) {
            gload_lds16(ksrc0 + (long)c * 8192 + r * 4096, kdst + r * 4096);
            gload_lds16(vsrc0 + (long)c * 128 + (long)r * 131072, vdst + r * 4096);
        }
        __syncthreads();

        int buf = 0;
        for (int j = c; j <= qb; j += 4) {
            const bool more = (j + 4 <= qb);
            if (more) {   // DMA next tile into alternate buffer, in flight during compute
                const int nb = buf ^ 1;
#pragma unroll
                for (int r = 0; r < 2; ++r) {
                    gload_lds16(ksrc0 + (long)(j + 4) * 8192 + r * 4096,
                                kdst + nb * 8192 + r * 4096);
                    gload_lds16(vsrc0 + (long)(j + 4) * 128 + (long)r * 131072,
                                vdst + nb * 8192 + r * 4096);
                }
            }
            const char* ksl = (const char*)&Ks[buf][0][0];
            const char* vsl = (const char*)&Vs[buf][0][0];

            // S = Q K^T ; per-wave S tile [16 x 64]
            floatx4 s_[4];
#pragma unroll
            for (int nt = 0; nt < 4; ++nt) {
                bf16x8 kf0 = *(const bf16x8*)(ksl + (nt * 16 + low) * 128 + cb0);
                bf16x8 kf1 = *(const bf16x8*)(ksl + (nt * 16 + low) * 128 + cb1);
                floatx4 z = (floatx4){0.f, 0.f, 0.f, 0.f};
                z = __builtin_amdgcn_mfma_f32_16x16x32_bf16(qf0, kf0, z, 0, 0, 0);
                z = __builtin_amdgcn_mfma_f32_16x16x32_bf16(qf1, kf1, z, 0, 0, 0);
                s_[nt] = z;
            }

            // p = exp2(s * 0.125*log2e); causal mask on diagonal tile; P strip -> LDS
            const bool diag = (j == qb);
#pragma unroll
            for (int nt = 0; nt < 4; ++nt) {
#pragma unroll
                for (int r = 0; r < 4; ++r) {
                    float p = __builtin_amdgcn_exp2f(s_[nt][r] * 0.180336880f);
                    if (diag && (nt * 16 + low) > (wave * 16 + quad * 4 + r)) p = 0.f;
                    Ps[wave][quad * 4 + r][nt * 16 + low] = (bf16)p;
                }
            }

            // O += P V ; l += P . ones  (Ps wave-private: lgkmcnt ordering suffices)
            bf16x8 pf0 = *(const bf16x8*)&Ps[wave][low][quad * 8];
            bf16x8 pf1 = *(const bf16x8*)&Ps[wave][low][32 + quad * 8];
#pragma unroll
            for (int nt = 0; nt < 4; ++nt) {
                bf16x8 vf0 = *(const bf16x8*)(vsl + (nt * 16 + low) * 128 + cb0);
                bf16x8 vf1 = *(const bf16x8*)(vsl + (nt * 16 + low) * 128 + cb1);
                o[nt] = __builtin_amdgcn_mfma_f32_16x16x32_bf16(pf0, vf0, o[nt], 0, 0, 0);
                o[nt] = __builtin_amdgcn_mfma_f32_16x16x32_bf16(pf1, vf1, o[nt], 0, 0, 0);
            }
            ol = __builtin_amdgcn_mfma_f32_16x16x32_bf16(pf0, ones, ol, 0, 0, 0);
            ol = __builtin_amdgcn_mfma_f32_16x16x32_bf16(pf1, ones, ol, 0, 0, 0);

            if (more) {   // barrier drains the DMA; swap buffers
                __syncthreads();
                buf ^= 1;
            }
        }
    }

    // epilogue via LDS transpose (alias retired Ks, 16KB >= 9.2KB): coalesced stores
    __syncthreads();
    bf16* Eo = (bf16*)&Ks[0][0][0];   // [64][72]: Eo[row][h]
#pragma unroll
    for (int nt = 0; nt < 4; ++nt)
#pragma unroll
        for (int r = 0; r < 4; ++r)
            Eo[(wave * 16 + quad * 4 + r) * 72 + nt * 16 + low] = (bf16)o[nt][r];
    __syncthreads();
    {
        const int row  = tid >> 2;
        const int col0 = (tid & 3) * 16;
        bf16* ob = Opart + (long)blockIdx.x * 4096 + row * 64 + col0;
        *(bf16x8*)(ob)     = *(const bf16x8*)&Eo[row * 72 + col0];
        *(bf16x8*)(ob + 8) = *(const bf16x8*)&Eo[row * 72 + col0 + 8];
    }
    if (low == 0) {
#pragma unroll
        for (int r = 0; r < 4; ++r)
            lpart[(long)blockIdx.x * 64 + wave * 16 + quad * 4 + r] = ol[r];
    }
}

// ---------------- Kernel 3: combine 4 chunks. out = sum_c Opart / sum_c lpart.
// grid 1024: 4 blocks per (b,qb) tile (16 rows each) for occupancy.
__global__ __launch_bounds__(256) void attn_combine(const bf16* __restrict__ Opart,
                                                    const float* __restrict__ lpart,
                                                    float* __restrict__ out) {
    const int tile = blockIdx.x >> 2;        // 0..255 = b*32+qb
    const int rg   = blockIdx.x & 3;
    const int tid  = threadIdx.x;
    const int row  = rg * 16 + (tid >> 4);   // 0..63
    const int col0 = (tid & 15) * 4;

    const bf16*  ob = Opart + (long)tile * 4 * 4096 + row * 64 + col0;
    const float* lb = lpart + (long)tile * 4 * 64 + row;

    float l = lb[0] + lb[64] + lb[128] + lb[192];
    float rl = 1.0f / l;

    float s[4] = {0.f, 0.f, 0.f, 0.f};
#pragma unroll
    for (int ch = 0; ch < 4; ++ch) {
        bf16x4 u = *(const bf16x4*)(ob + ch * 4096);
#pragma unroll
        for (int i = 0; i < 4; ++i) s[i] += (float)u[i];
    }
    float4 w;
    w.x = s[0] * rl; w.y = s[1] * rl; w.z = s[2] * rl; w.w = s[3] * rl;
    *(float4*)(out + (long)tile * 4096 + row * 64 + col0) = w;
}

extern "C" void kernel_launch(void* const* d_in, const int* in_sizes, int n_in,
                              void* d_out, int out_size, void* d_ws, size_t ws_size,
                              hipStream_t stream) {
    const float* x  = (const float*)d_in[0];
    const float* Wk = (const float*)d_in[1];
    const float* Wv = (const float*)d_in[2];
    float* out = (float*)d_out;

    char* ws = (char*)d_ws;
    bf16*  Wb    = (bf16*)ws;                           // 256 KB
    bf16*  Kbuf  = (bf16*)(ws + (1 << 20));             // 2 MB
    bf16*  Vt    = (bf16*)(ws + (3 << 20));             // 2 MB
    bf16*  Opart = (bf16*)(ws + (5 << 20));             // 8 MB
    float* lpart = (float*)(ws + (13 << 20));           // 256 KB

    wconv_kernel<<<128, 256, 0, stream>>>(Wk, Wv, Wb);
    // DIAGNOSTIC: proj grid x9 (replicas recompute identical tiles) so the single
    // dispatch exceeds the 41us fills and surfaces in top-5 WITH FULL COUNTERS.
    proj_kernel<<<4608, 256, 0, stream>>>(x, Wb, Kbuf, Vt);
    attn_kernel<<<1024, 256, 0, stream>>>(Kbuf, Vt, Opart, lpart);
    attn_combine<<<1024, 256, 0, stream>>>(Opart, lpart, out);
}

// Round 5
// 170.203 us; speedup vs baseline: 1.4948x; 1.2101x over previous
//
#include <hip/hip_runtime.h>

// Head: k = x@Wk^T; q = k (source bug); wei = softmax(causal(q k^T / 8)); v = x@Wv^T; out = wei@v
// B=8, T=2048, C=1024, H=64. fp32 in/out, bf16 MFMA internally.
//
// R10 -> R11: diagnostics complete. Budget: proj ~12us (AT its 64MB-x HBM floor; frozen),
// attn ~15.8us (3x off compute floor), ~90us fixed harness fill overhead (untouchable).
// This round: attn drops K/V LDS staging entirely (K/V = 4MB, L2/L3-resident; staging
// L2-fit data is pure overhead) and reads fragments direct from global -- geometry is
// fully line-efficient (128B rows consumed whole by kf0/kf1 and vf0/vf1 pairs).
// Main loop is now BARRIER-FREE (Ps + epilogue transpose are wave-private), LDS 41->9.2KB,
// occupancy 3 -> ~5 blocks/CU. proj restored to grid 512 (R7-banked verbatim).

typedef __bf16 bf16;
typedef __bf16 bf16x4 __attribute__((ext_vector_type(4)));
typedef __bf16 bf16x8 __attribute__((ext_vector_type(8)));
typedef float  floatx4 __attribute__((ext_vector_type(4)));

#define T_LEN 2048
#define HEAD  64
#define CEMB  1024

static __device__ __forceinline__ bf16x8 cvt2(float4 a, float4 b) {
    bf16x8 r;
    r[0] = (bf16)a.x; r[1] = (bf16)a.y; r[2] = (bf16)a.z; r[3] = (bf16)a.w;
    r[4] = (bf16)b.x; r[5] = (bf16)b.y; r[6] = (bf16)b.z; r[7] = (bf16)b.w;
    return r;
}

// async 16B global->LDS. LDS dest is wave-uniform base + lane*16 (linear);
// global src is per-lane. Completion tracked by vmcnt; __syncthreads drains it.
static __device__ __forceinline__ void gload_lds16(const void* g, void* l) {
    __builtin_amdgcn_global_load_lds(
        (const __attribute__((address_space(1))) unsigned int*)(unsigned long long)g,
        (__attribute__((address_space(3))) unsigned int*)(unsigned long long)l,
        16, 0, 0);
}

// ---------------- Kernel 0: W fp32 -> bf16, [Wk;Wv] concat as Wb[128][1024]
__global__ __launch_bounds__(256) void wconv_kernel(const float* __restrict__ Wk,
                                                    const float* __restrict__ Wv,
                                                    bf16* __restrict__ Wb) {
    int i = (blockIdx.x * 256 + threadIdx.x) * 4;   // grid 128 covers 131072
    const float* src = (i < 64 * 1024) ? (Wk + i) : (Wv + (i - 64 * 1024));
    float4 f = *(const float4*)src;
    bf16x4 v;
    v[0] = (bf16)f.x; v[1] = (bf16)f.y; v[2] = (bf16)f.z; v[3] = (bf16)f.w;
    *(bf16x4*)&Wb[i] = v;
}

// ---------------- Kernel 1: projection GEMM. grid 512, tile 32 rows x 128 cols, BK=64.
// At its HBM roofline (~12us streaming the 64MB x): R7-banked structure, frozen.
__global__ __launch_bounds__(256) void proj_kernel(const float* __restrict__ x,
                                                   const bf16* __restrict__ Wb,
                                                   bf16* __restrict__ Kbuf,
                                                   bf16* __restrict__ Vt) {
    __shared__ __align__(16) bf16 As[2][32][72];
    __shared__ __align__(16) bf16 Bs[2][128][64];   // linear rows (128B), XOR-swizzled cols

    const int tid  = threadIdx.x;
    const int wave = tid >> 6;
    const int lane = tid & 63;
    const int quad = lane >> 4;
    const int low  = lane & 15;

    const long row0 = (long)blockIdx.x * 32;

    const int a_row = tid >> 3;          // 0..31, 8 fp32/thread
    const int a_col = (tid & 7) * 8;
    const float* abase = x + (row0 + a_row) * CEMB + a_col;

    // B staging geometry: linear LDS offset o=(r*256+tid)*16 -> row=r*32+(tid>>3),
    // col byte cbp=(tid&7)*16. Source col = cbp ^ ((row&7)<<4) (pre-swizzle).
    const int brow = tid >> 3;
    const int cbp  = (tid & 7) * 16;
    const int bsw  = cbp ^ ((brow & 7) << 4);
    const char* bsrc0 = (const char*)Wb + (long)brow * (CEMB * 2) + bsw;  // +r*65536 +s*128
    char* bdst = (char*)&Bs[0][0][0] + wave * 1024;                       // +nb*16384 +r*4096

    const int strip = wave & 1;          // 16-row M strip
    const int nhalf = wave >> 1;         // 0 -> K n-tiles, 1 -> V n-tiles
    const int nq    = nhalf * 4;

    floatx4 acc[4];
#pragma unroll
    for (int i = 0; i < 4; ++i) acc[i] = (floatx4){0.f, 0.f, 0.f, 0.f};

    float4 apf[2][2];

    // prologue: A step0 -> regs -> LDS0; B step0 DMA -> Bs[0]; A step1 -> regs
    apf[0][0] = ((const float4*)abase)[0];
    apf[0][1] = ((const float4*)abase)[1];
#pragma unroll
    for (int r = 0; r < 4; ++r)
        gload_lds16(bsrc0 + (long)r * 65536, bdst + r * 4096);
    *(bf16x8*)&As[0][a_row][a_col] = cvt2(apf[0][0], apf[0][1]);
    apf[1][0] = ((const float4*)(abase + 64))[0];
    apf[1][1] = ((const float4*)(abase + 64))[1];
    __syncthreads();   // drains B(0) DMA

    const int bswz = (low & 7) << 4;
    int buf = 0;
    for (int s = 0; s < 16; ++s) {
        if (s < 15) {
            const int q  = (s + 1) & 1;
            const int nb = buf ^ 1;
            // A(s+1) regs -> LDS[nb]; B(s+1) DMA -> Bs[nb] (in flight during compute)
            *(bf16x8*)&As[nb][a_row][a_col] = cvt2(apf[q][0], apf[q][1]);
#pragma unroll
            for (int r = 0; r < 4; ++r)
                gload_lds16(bsrc0 + (long)r * 65536 + (s + 1) * 128,
                            bdst + nb * 16384 + r * 4096);
        }
        if (s < 14) {   // A(s+2) global -> regs: full-iteration latency cover
            const int q  = s & 1;
            const int k0 = (s + 2) * 64;
            apf[q][0] = ((const float4*)(abase + k0))[0];
            apf[q][1] = ((const float4*)(abase + k0))[1];
        }
        // compute current step
        const char* bsl = (const char*)&Bs[buf][0][0];
#pragma unroll
        for (int ks = 0; ks < 2; ++ks) {
            bf16x8 afrag = *(const bf16x8*)&As[buf][strip * 16 + low][ks * 32 + quad * 8];
            const int cb = (ks * 64 + quad * 16) ^ bswz;
#pragma unroll
            for (int i = 0; i < 4; ++i) {
                bf16x8 bfrag = *(const bf16x8*)(bsl + ((nq + i) * 16 + low) * 128 + cb);
                acc[i] = __builtin_amdgcn_mfma_f32_16x16x32_bf16(afrag, bfrag, acc[i], 0, 0, 0);
            }
        }
        if (s < 15) {
            __syncthreads();
            buf ^= 1;
        }
    }

    // epilogue via LDS transpose (alias retired Bs): coalesced 16B stores.
    __syncthreads();
    bf16* Ek = (bf16*)&Bs[0][0][0];   // [32][72]: Ek[t][h]
    bf16* Ev = (bf16*)&Bs[1][0][0];   // [64][36]: Ev[h][t]
    if (nhalf == 0) {
#pragma unroll
        for (int i = 0; i < 4; ++i)
#pragma unroll
            for (int r = 0; r < 4; ++r)
                Ek[(strip * 16 + quad * 4 + r) * 72 + i * 16 + low] = (bf16)acc[i][r];
    } else {
#pragma unroll
        for (int i = 0; i < 4; ++i)
#pragma unroll
            for (int r = 0; r < 4; ++r)
                Ev[(i * 16 + low) * 36 + strip * 16 + quad * 4 + r] = (bf16)acc[i][r];
    }
    __syncthreads();

    const long bidx  = row0 >> 11;
    const int  tloc0 = (int)(row0 & 2047);
    {   // K copy: 16B contiguous, fully coalesced
        const int t  = tid >> 3;
        const int h0 = (tid & 7) * 8;
        *(bf16x8*)&Kbuf[(bidx * T_LEN + tloc0 + t) * HEAD + h0] = *(const bf16x8*)&Ek[t * 72 + h0];
    }
    {   // V copy: 16B contiguous per h-row
        const int h  = tid >> 2;
        const int t0 = (tid & 3) * 8;
        *(bf16x8*)&Vt[(bidx * HEAD + h) * T_LEN + tloc0 + t0] = *(const bf16x8*)&Ev[h * 36 + t0];
    }
}

// ---------------- Kernel 2: attention partial. q=k, causal, scale 1/8, fixed-max softmax.
// blockIdx.x = ((b*32 + qb)*4 + c); chunk c: kv tiles j in {c, c+4, ...} <= qb (max 8 iters).
// K/V read DIRECT from global (L2/L3-resident; rows fully line-efficient). Only Ps in
// LDS (wave-private) -> barrier-free main loop, 9.2KB LDS, high occupancy.
__global__ __launch_bounds__(256) void attn_kernel(const bf16* __restrict__ Kbuf,
                                                   const bf16* __restrict__ Vt,
                                                   bf16* __restrict__ Opart,
                                                   float* __restrict__ lpart) {
    __shared__ __align__(16) bf16 Ps[4][16][72];   // per-wave private; aliased as Eo in epilogue

    const int tid  = threadIdx.x;
    const int wave = tid >> 6;
    const int lane = tid & 63;
    const int quad = lane >> 4;
    const int low  = lane & 15;

    const int c  = blockIdx.x & 3;
    const int qb = (blockIdx.x >> 2) & 31;
    const int b  = blockIdx.x >> 7;

    const bf16* kbase = Kbuf + (long)b * T_LEN * HEAD;
    const bf16* vbase = Vt + (long)b * HEAD * T_LEN;

    // Q fragments (A-layout) direct from global (once per block)
    const bf16* qrow = kbase + (qb * 64 + wave * 16 + low) * HEAD + quad * 8;
    const bf16x8 qf0 = *(const bf16x8*)(qrow);
    const bf16x8 qf1 = *(const bf16x8*)(qrow + 32);

    bf16x8 ones;
#pragma unroll
    for (int i = 0; i < 8; ++i) ones[i] = (bf16)1.0f;

    floatx4 o[4], ol;
#pragma unroll
    for (int nt = 0; nt < 4; ++nt) o[nt] = (floatx4){0.f, 0.f, 0.f, 0.f};
    ol = (floatx4){0.f, 0.f, 0.f, 0.f};

    if (c <= qb) {
        for (int j = c; j <= qb; j += 4) {
            const bf16* ktile = kbase + (long)(j * 64) * HEAD;   // rows 64, stride 64 bf16
            const bf16* vtile = vbase + j * 64;                  // [h][t-slice], stride 2048

            // S = Q K^T ; per-wave S tile [16 x 64]; K frags direct (full 128B rows)
            floatx4 s_[4];
#pragma unroll
            for (int nt = 0; nt < 4; ++nt) {
                const bf16* kr = ktile + (nt * 16 + low) * HEAD + quad * 8;
                bf16x8 kf0 = *(const bf16x8*)(kr);
                bf16x8 kf1 = *(const bf16x8*)(kr + 32);
                floatx4 z = (floatx4){0.f, 0.f, 0.f, 0.f};
                z = __builtin_amdgcn_mfma_f32_16x16x32_bf16(qf0, kf0, z, 0, 0, 0);
                z = __builtin_amdgcn_mfma_f32_16x16x32_bf16(qf1, kf1, z, 0, 0, 0);
                s_[nt] = z;
            }

            // p = exp2(s * 0.125*log2e); causal mask on diagonal tile; P strip -> LDS
            const bool diag = (j == qb);
#pragma unroll
            for (int nt = 0; nt < 4; ++nt) {
#pragma unroll
                for (int r = 0; r < 4; ++r) {
                    float p = __builtin_amdgcn_exp2f(s_[nt][r] * 0.180336880f);
                    if (diag && (nt * 16 + low) > (wave * 16 + quad * 4 + r)) p = 0.f;
                    Ps[wave][quad * 4 + r][nt * 16 + low] = (bf16)p;
                }
            }

            // O += P V ; l += P . ones  (Ps wave-private: lgkmcnt ordering suffices)
            bf16x8 pf0 = *(const bf16x8*)&Ps[wave][low][quad * 8];
            bf16x8 pf1 = *(const bf16x8*)&Ps[wave][low][32 + quad * 8];
#pragma unroll
            for (int nt = 0; nt < 4; ++nt) {
                const bf16* vr = vtile + (long)(nt * 16 + low) * T_LEN + quad * 8;
                bf16x8 vf0 = *(const bf16x8*)(vr);
                bf16x8 vf1 = *(const bf16x8*)(vr + 32);
                o[nt] = __builtin_amdgcn_mfma_f32_16x16x32_bf16(pf0, vf0, o[nt], 0, 0, 0);
                o[nt] = __builtin_amdgcn_mfma_f32_16x16x32_bf16(pf1, vf1, o[nt], 0, 0, 0);
            }
            ol = __builtin_amdgcn_mfma_f32_16x16x32_bf16(pf0, ones, ol, 0, 0, 0);
            ol = __builtin_amdgcn_mfma_f32_16x16x32_bf16(pf1, ones, ol, 0, 0, 0);
        }
    }

    // epilogue via LDS transpose (alias Ps: same 9.2KB, wave's rows = its Ps block)
    __syncthreads();
    bf16* Eo = (bf16*)&Ps[0][0][0];   // [64][72]: Eo[row][h]
#pragma unroll
    for (int nt = 0; nt < 4; ++nt)
#pragma unroll
        for (int r = 0; r < 4; ++r)
            Eo[(wave * 16 + quad * 4 + r) * 72 + nt * 16 + low] = (bf16)o[nt][r];
    __syncthreads();
    {
        const int row  = tid >> 2;         // wave w reads rows w*16..w*16+15 (own block)
        const int col0 = (tid & 3) * 16;
        bf16* ob = Opart + (long)blockIdx.x * 4096 + row * 64 + col0;
        *(bf16x8*)(ob)     = *(const bf16x8*)&Eo[row * 72 + col0];
        *(bf16x8*)(ob + 8) = *(const bf16x8*)&Eo[row * 72 + col0 + 8];
    }
    if (low == 0) {
#pragma unroll
        for (int r = 0; r < 4; ++r)
            lpart[(long)blockIdx.x * 64 + wave * 16 + quad * 4 + r] = ol[r];
    }
}

// ---------------- Kernel 3: combine 4 chunks. out = sum_c Opart / sum_c lpart.
// grid 1024: 4 blocks per (b,qb) tile (16 rows each) for occupancy.
__global__ __launch_bounds__(256) void attn_combine(const bf16* __restrict__ Opart,
                                                    const float* __restrict__ lpart,
                                                    float* __restrict__ out) {
    const int tile = blockIdx.x >> 2;        // 0..255 = b*32+qb
    const int rg   = blockIdx.x & 3;
    const int tid  = threadIdx.x;
    const int row  = rg * 16 + (tid >> 4);   // 0..63
    const int col0 = (tid & 15) * 4;

    const bf16*  ob = Opart + (long)tile * 4 * 4096 + row * 64 + col0;
    const float* lb = lpart + (long)tile * 4 * 64 + row;

    float l = lb[0] + lb[64] + lb[128] + lb[192];
    float rl = 1.0f / l;

    float s[4] = {0.f, 0.f, 0.f, 0.f};
#pragma unroll
    for (int ch = 0; ch < 4; ++ch) {
        bf16x4 u = *(const bf16x4*)(ob + ch * 4096);
#pragma unroll
        for (int i = 0; i < 4; ++i) s[i] += (float)u[i];
    }
    float4 w;
    w.x = s[0] * rl; w.y = s[1] * rl; w.z = s[2] * rl; w.w = s[3] * rl;
    *(float4*)(out + (long)tile * 4096 + row * 64 + col0) = w;
}

extern "C" void kernel_launch(void* const* d_in, const int* in_sizes, int n_in,
                              void* d_out, int out_size, void* d_ws, size_t ws_size,
                              hipStream_t stream) {
    const float* x  = (const float*)d_in[0];
    const float* Wk = (const float*)d_in[1];
    const float* Wv = (const float*)d_in[2];
    float* out = (float*)d_out;

    char* ws = (char*)d_ws;
    bf16*  Wb    = (bf16*)ws;                           // 256 KB
    bf16*  Kbuf  = (bf16*)(ws + (1 << 20));             // 2 MB
    bf16*  Vt    = (bf16*)(ws + (3 << 20));             // 2 MB
    bf16*  Opart = (bf16*)(ws + (5 << 20));             // 8 MB
    float* lpart = (float*)(ws + (13 << 20));           // 256 KB

    wconv_kernel<<<128, 256, 0, stream>>>(Wk, Wv, Wb);
    proj_kernel<<<512, 256, 0, stream>>>(x, Wb, Kbuf, Vt);
    attn_kernel<<<1024, 256, 0, stream>>>(Kbuf, Vt, Opart, lpart);
    attn_combine<<<1024, 256, 0, stream>>>(Opart, lpart, out);
}

// Round 6
// 130.173 us; speedup vs baseline: 1.9544x; 1.3075x over previous
//
#include <hip/hip_runtime.h>

// Head: k = x@Wk^T; q = k (source bug); wei = softmax(causal(q k^T / 8)); v = x@Wv^T; out = wei@v
// B=8, T=2048, C=1024, H=64. fp32 in/out, bf16 MFMA internally.
//
// R11 -> R12: R11 (direct-global attn) regressed 15.8 -> 62.4us/dispatch: latency-bound
// (MfmaUtil 2.8%, HBM 3%) -- LDS staging WAS the latency hiding. Reverted to banked R7
// attn. One surgical change: Ps [4][16][72] (9.2KB, padded) -> [4][16][64] (8KB,
// XOR-swizzled byte ^= (row&7)<<4 both sides). Block LDS 41984 -> 40960 B: exactly
// 4 blocks/CU (4x40960 = 160KiB) instead of 3 -> +33% TLP on the latency chain.
// proj frozen at its HBM floor (~12us); fixed harness fills ~90us are untouchable.

typedef __bf16 bf16;
typedef __bf16 bf16x4 __attribute__((ext_vector_type(4)));
typedef __bf16 bf16x8 __attribute__((ext_vector_type(8)));
typedef float  floatx4 __attribute__((ext_vector_type(4)));

#define T_LEN 2048
#define HEAD  64
#define CEMB  1024

static __device__ __forceinline__ bf16x8 cvt2(float4 a, float4 b) {
    bf16x8 r;
    r[0] = (bf16)a.x; r[1] = (bf16)a.y; r[2] = (bf16)a.z; r[3] = (bf16)a.w;
    r[4] = (bf16)b.x; r[5] = (bf16)b.y; r[6] = (bf16)b.z; r[7] = (bf16)b.w;
    return r;
}

// async 16B global->LDS. LDS dest is wave-uniform base + lane*16 (linear);
// global src is per-lane. Completion tracked by vmcnt; __syncthreads drains it.
static __device__ __forceinline__ void gload_lds16(const void* g, void* l) {
    __builtin_amdgcn_global_load_lds(
        (const __attribute__((address_space(1))) unsigned int*)(unsigned long long)g,
        (__attribute__((address_space(3))) unsigned int*)(unsigned long long)l,
        16, 0, 0);
}

// ---------------- Kernel 0: W fp32 -> bf16, [Wk;Wv] concat as Wb[128][1024]
__global__ __launch_bounds__(256) void wconv_kernel(const float* __restrict__ Wk,
                                                    const float* __restrict__ Wv,
                                                    bf16* __restrict__ Wb) {
    int i = (blockIdx.x * 256 + threadIdx.x) * 4;   // grid 128 covers 131072
    const float* src = (i < 64 * 1024) ? (Wk + i) : (Wv + (i - 64 * 1024));
    float4 f = *(const float4*)src;
    bf16x4 v;
    v[0] = (bf16)f.x; v[1] = (bf16)f.y; v[2] = (bf16)f.z; v[3] = (bf16)f.w;
    *(bf16x4*)&Wb[i] = v;
}

// ---------------- Kernel 1: projection GEMM. grid 512, tile 32 rows x 128 cols, BK=64.
// At its HBM roofline (~12us streaming the 64MB x): R7-banked structure, frozen.
__global__ __launch_bounds__(256) void proj_kernel(const float* __restrict__ x,
                                                   const bf16* __restrict__ Wb,
                                                   bf16* __restrict__ Kbuf,
                                                   bf16* __restrict__ Vt) {
    __shared__ __align__(16) bf16 As[2][32][72];
    __shared__ __align__(16) bf16 Bs[2][128][64];   // linear rows (128B), XOR-swizzled cols

    const int tid  = threadIdx.x;
    const int wave = tid >> 6;
    const int lane = tid & 63;
    const int quad = lane >> 4;
    const int low  = lane & 15;

    const long row0 = (long)blockIdx.x * 32;

    const int a_row = tid >> 3;          // 0..31, 8 fp32/thread
    const int a_col = (tid & 7) * 8;
    const float* abase = x + (row0 + a_row) * CEMB + a_col;

    // B staging geometry: linear LDS offset o=(r*256+tid)*16 -> row=r*32+(tid>>3),
    // col byte cbp=(tid&7)*16. Source col = cbp ^ ((row&7)<<4) (pre-swizzle).
    const int brow = tid >> 3;
    const int cbp  = (tid & 7) * 16;
    const int bsw  = cbp ^ ((brow & 7) << 4);
    const char* bsrc0 = (const char*)Wb + (long)brow * (CEMB * 2) + bsw;  // +r*65536 +s*128
    char* bdst = (char*)&Bs[0][0][0] + wave * 1024;                       // +nb*16384 +r*4096

    const int strip = wave & 1;          // 16-row M strip
    const int nhalf = wave >> 1;         // 0 -> K n-tiles, 1 -> V n-tiles
    const int nq    = nhalf * 4;

    floatx4 acc[4];
#pragma unroll
    for (int i = 0; i < 4; ++i) acc[i] = (floatx4){0.f, 0.f, 0.f, 0.f};

    float4 apf[2][2];

    // prologue: A step0 -> regs -> LDS0; B step0 DMA -> Bs[0]; A step1 -> regs
    apf[0][0] = ((const float4*)abase)[0];
    apf[0][1] = ((const float4*)abase)[1];
#pragma unroll
    for (int r = 0; r < 4; ++r)
        gload_lds16(bsrc0 + (long)r * 65536, bdst + r * 4096);
    *(bf16x8*)&As[0][a_row][a_col] = cvt2(apf[0][0], apf[0][1]);
    apf[1][0] = ((const float4*)(abase + 64))[0];
    apf[1][1] = ((const float4*)(abase + 64))[1];
    __syncthreads();   // drains B(0) DMA

    const int bswz = (low & 7) << 4;
    int buf = 0;
    for (int s = 0; s < 16; ++s) {
        if (s < 15) {
            const int q  = (s + 1) & 1;
            const int nb = buf ^ 1;
            // A(s+1) regs -> LDS[nb]; B(s+1) DMA -> Bs[nb] (in flight during compute)
            *(bf16x8*)&As[nb][a_row][a_col] = cvt2(apf[q][0], apf[q][1]);
#pragma unroll
            for (int r = 0; r < 4; ++r)
                gload_lds16(bsrc0 + (long)r * 65536 + (s + 1) * 128,
                            bdst + nb * 16384 + r * 4096);
        }
        if (s < 14) {   // A(s+2) global -> regs: full-iteration latency cover
            const int q  = s & 1;
            const int k0 = (s + 2) * 64;
            apf[q][0] = ((const float4*)(abase + k0))[0];
            apf[q][1] = ((const float4*)(abase + k0))[1];
        }
        // compute current step
        const char* bsl = (const char*)&Bs[buf][0][0];
#pragma unroll
        for (int ks = 0; ks < 2; ++ks) {
            bf16x8 afrag = *(const bf16x8*)&As[buf][strip * 16 + low][ks * 32 + quad * 8];
            const int cb = (ks * 64 + quad * 16) ^ bswz;
#pragma unroll
            for (int i = 0; i < 4; ++i) {
                bf16x8 bfrag = *(const bf16x8*)(bsl + ((nq + i) * 16 + low) * 128 + cb);
                acc[i] = __builtin_amdgcn_mfma_f32_16x16x32_bf16(afrag, bfrag, acc[i], 0, 0, 0);
            }
        }
        if (s < 15) {
            __syncthreads();
            buf ^= 1;
        }
    }

    // epilogue via LDS transpose (alias retired Bs): coalesced 16B stores.
    __syncthreads();
    bf16* Ek = (bf16*)&Bs[0][0][0];   // [32][72]: Ek[t][h]
    bf16* Ev = (bf16*)&Bs[1][0][0];   // [64][36]: Ev[h][t]
    if (nhalf == 0) {
#pragma unroll
        for (int i = 0; i < 4; ++i)
#pragma unroll
            for (int r = 0; r < 4; ++r)
                Ek[(strip * 16 + quad * 4 + r) * 72 + i * 16 + low] = (bf16)acc[i][r];
    } else {
#pragma unroll
        for (int i = 0; i < 4; ++i)
#pragma unroll
            for (int r = 0; r < 4; ++r)
                Ev[(i * 16 + low) * 36 + strip * 16 + quad * 4 + r] = (bf16)acc[i][r];
    }
    __syncthreads();

    const long bidx  = row0 >> 11;
    const int  tloc0 = (int)(row0 & 2047);
    {   // K copy: 16B contiguous, fully coalesced
        const int t  = tid >> 3;
        const int h0 = (tid & 7) * 8;
        *(bf16x8*)&Kbuf[(bidx * T_LEN + tloc0 + t) * HEAD + h0] = *(const bf16x8*)&Ek[t * 72 + h0];
    }
    {   // V copy: 16B contiguous per h-row
        const int h  = tid >> 2;
        const int t0 = (tid & 3) * 8;
        *(bf16x8*)&Vt[(bidx * HEAD + h) * T_LEN + tloc0 + t0] = *(const bf16x8*)&Ev[h * 36 + t0];
    }
}

// ---------------- Kernel 2: attention partial. q=k, causal, scale 1/8, fixed-max softmax.
// blockIdx.x = ((b*32 + qb)*4 + c); chunk c: kv tiles j in {c, c+4, ...} <= qb (max 8 iters).
// K/V staged via global_load_lds into swizzled Ks/Vs[2][64][64]; 1 barrier/iter.
// Ps XOR-swizzled [4][16][64] (8KB): block LDS 40960 B -> exactly 4 blocks/CU.
__global__ __launch_bounds__(256) void attn_kernel(const bf16* __restrict__ Kbuf,
                                                   const bf16* __restrict__ Vt,
                                                   bf16* __restrict__ Opart,
                                                   float* __restrict__ lpart) {
    __shared__ __align__(16) bf16 Ks[2][64][64];
    __shared__ __align__(16) bf16 Vs[2][64][64];   // [h][kv]
    __shared__ __align__(16) bf16 Ps[4][16][64];   // per-wave private, XOR-swizzled

    const int tid  = threadIdx.x;
    const int wave = tid >> 6;
    const int lane = tid & 63;
    const int quad = lane >> 4;
    const int low  = lane & 15;

    const int c  = blockIdx.x & 3;
    const int qb = (blockIdx.x >> 2) & 31;
    const int b  = blockIdx.x >> 7;

    const bf16* kbase = Kbuf + (long)b * T_LEN * HEAD;
    const bf16* vbase = Vt + (long)b * HEAD * T_LEN;

    // Q fragments (A-layout) direct from global (once per block)
    const bf16* qrow = kbase + (qb * 64 + wave * 16 + low) * HEAD + quad * 8;
    const bf16x8 qf0 = *(const bf16x8*)(qrow);
    const bf16x8 qf1 = *(const bf16x8*)(qrow + 32);

    bf16x8 ones;
#pragma unroll
    for (int i = 0; i < 8; ++i) ones[i] = (bf16)1.0f;

    floatx4 o[4], ol;
#pragma unroll
    for (int nt = 0; nt < 4; ++nt) o[nt] = (floatx4){0.f, 0.f, 0.f, 0.f};
    ol = (floatx4){0.f, 0.f, 0.f, 0.f};

    // staging geometry: linear o=(r*256+tid)*16 -> row=r*32+(tid>>3), cbp=(tid&7)*16.
    const int srow = tid >> 3;
    const int cbp  = (tid & 7) * 16;
    const int ssw  = cbp ^ ((srow & 7) << 4);
    const char* ksrc0 = (const char*)kbase + (long)srow * 128  + ssw;  // +j*8192 +r*4096
    const char* vsrc0 = (const char*)vbase + (long)srow * 4096 + ssw;  // +j*128  +r*131072
    char* kdst = (char*)&Ks[0][0][0] + wave * 1024;
    char* vdst = (char*)&Vs[0][0][0] + wave * 1024;

    const int sw  = (low & 7) << 4;
    const int cb0 = (quad * 16) ^ sw;
    const int cb1 = (64 + quad * 16) ^ sw;

    // Ps swizzle: write P[row][col] at byte (2*col) ^ ((row&7)<<4); read b128 same XOR.
    char* psbase = (char*)&Ps[wave][0][0];

    if (c <= qb) {
        // prologue: stage tile j=c into buf 0
#pragma unroll
        for (int r = 0; r < 2; ++r) {
            gload_lds16(ksrc0 + (long)c * 8192 + r * 4096, kdst + r * 4096);
            gload_lds16(vsrc0 + (long)c * 128 + (long)r * 131072, vdst + r * 4096);
        }
        __syncthreads();

        int buf = 0;
        for (int j = c; j <= qb; j += 4) {
            const bool more = (j + 4 <= qb);
            if (more) {   // DMA next tile into alternate buffer, in flight during compute
                const int nb = buf ^ 1;
#pragma unroll
                for (int r = 0; r < 2; ++r) {
                    gload_lds16(ksrc0 + (long)(j + 4) * 8192 + r * 4096,
                                kdst + nb * 8192 + r * 4096);
                    gload_lds16(vsrc0 + (long)(j + 4) * 128 + (long)r * 131072,
                                vdst + nb * 8192 + r * 4096);
                }
            }
            const char* ksl = (const char*)&Ks[buf][0][0];
            const char* vsl = (const char*)&Vs[buf][0][0];

            // S = Q K^T ; per-wave S tile [16 x 64]
            floatx4 s_[4];
#pragma unroll
            for (int nt = 0; nt < 4; ++nt) {
                bf16x8 kf0 = *(const bf16x8*)(ksl + (nt * 16 + low) * 128 + cb0);
                bf16x8 kf1 = *(const bf16x8*)(ksl + (nt * 16 + low) * 128 + cb1);
                floatx4 z = (floatx4){0.f, 0.f, 0.f, 0.f};
                z = __builtin_amdgcn_mfma_f32_16x16x32_bf16(qf0, kf0, z, 0, 0, 0);
                z = __builtin_amdgcn_mfma_f32_16x16x32_bf16(qf1, kf1, z, 0, 0, 0);
                s_[nt] = z;
            }

            // p = exp2(s * 0.125*log2e); causal mask on diagonal tile; P strip -> LDS
            const bool diag = (j == qb);
#pragma unroll
            for (int nt = 0; nt < 4; ++nt) {
#pragma unroll
                for (int r = 0; r < 4; ++r) {
                    float p = __builtin_amdgcn_exp2f(s_[nt][r] * 0.180336880f);
                    if (diag && (nt * 16 + low) > (wave * 16 + quad * 4 + r)) p = 0.f;
                    const int prow = quad * 4 + r;
                    *(bf16*)(psbase + prow * 128 +
                             ((2 * (nt * 16 + low)) ^ ((prow & 7) << 4))) = (bf16)p;
                }
            }

            // O += P V ; l += P . ones  (Ps wave-private: lgkmcnt ordering suffices)
            bf16x8 pf0 = *(const bf16x8*)(psbase + low * 128 + ((quad * 16) ^ sw));
            bf16x8 pf1 = *(const bf16x8*)(psbase + low * 128 + ((64 + quad * 16) ^ sw));
#pragma unroll
            for (int nt = 0; nt < 4; ++nt) {
                bf16x8 vf0 = *(const bf16x8*)(vsl + (nt * 16 + low) * 128 + cb0);
                bf16x8 vf1 = *(const bf16x8*)(vsl + (nt * 16 + low) * 128 + cb1);
                o[nt] = __builtin_amdgcn_mfma_f32_16x16x32_bf16(pf0, vf0, o[nt], 0, 0, 0);
                o[nt] = __builtin_amdgcn_mfma_f32_16x16x32_bf16(pf1, vf1, o[nt], 0, 0, 0);
            }
            ol = __builtin_amdgcn_mfma_f32_16x16x32_bf16(pf0, ones, ol, 0, 0, 0);
            ol = __builtin_amdgcn_mfma_f32_16x16x32_bf16(pf1, ones, ol, 0, 0, 0);

            if (more) {   // barrier drains the DMA; swap buffers
                __syncthreads();
                buf ^= 1;
            }
        }
    }

    // epilogue via LDS transpose (alias retired Ks, 16KB >= 9.2KB): coalesced stores
    __syncthreads();
    bf16* Eo = (bf16*)&Ks[0][0][0];   // [64][72]: Eo[row][h]
#pragma unroll
    for (int nt = 0; nt < 4; ++nt)
#pragma unroll
        for (int r = 0; r < 4; ++r)
            Eo[(wave * 16 + quad * 4 + r) * 72 + nt * 16 + low] = (bf16)o[nt][r];
    __syncthreads();
    {
        const int row  = tid >> 2;
        const int col0 = (tid & 3) * 16;
        bf16* ob = Opart + (long)blockIdx.x * 4096 + row * 64 + col0;
        *(bf16x8*)(ob)     = *(const bf16x8*)&Eo[row * 72 + col0];
        *(bf16x8*)(ob + 8) = *(const bf16x8*)&Eo[row * 72 + col0 + 8];
    }
    if (low == 0) {
#pragma unroll
        for (int r = 0; r < 4; ++r)
            lpart[(long)blockIdx.x * 64 + wave * 16 + quad * 4 + r] = ol[r];
    }
}

// ---------------- Kernel 3: combine 4 chunks. out = sum_c Opart / sum_c lpart.
// grid 1024: 4 blocks per (b,qb) tile (16 rows each) for occupancy.
__global__ __launch_bounds__(256) void attn_combine(const bf16* __restrict__ Opart,
                                                    const float* __restrict__ lpart,
                                                    float* __restrict__ out) {
    const int tile = blockIdx.x >> 2;        // 0..255 = b*32+qb
    const int rg   = blockIdx.x & 3;
    const int tid  = threadIdx.x;
    const int row  = rg * 16 + (tid >> 4);   // 0..63
    const int col0 = (tid & 15) * 4;

    const bf16*  ob = Opart + (long)tile * 4 * 4096 + row * 64 + col0;
    const float* lb = lpart + (long)tile * 4 * 64 + row;

    float l = lb[0] + lb[64] + lb[128] + lb[192];
    float rl = 1.0f / l;

    float s[4] = {0.f, 0.f, 0.f, 0.f};
#pragma unroll
    for (int ch = 0; ch < 4; ++ch) {
        bf16x4 u = *(const bf16x4*)(ob + ch * 4096);
#pragma unroll
        for (int i = 0; i < 4; ++i) s[i] += (float)u[i];
    }
    float4 w;
    w.x = s[0] * rl; w.y = s[1] * rl; w.z = s[2] * rl; w.w = s[3] * rl;
    *(float4*)(out + (long)tile * 4096 + row * 64 + col0) = w;
}

extern "C" void kernel_launch(void* const* d_in, const int* in_sizes, int n_in,
                              void* d_out, int out_size, void* d_ws, size_t ws_size,
                              hipStream_t stream) {
    const float* x  = (const float*)d_in[0];
    const float* Wk = (const float*)d_in[1];
    const float* Wv = (const float*)d_in[2];
    float* out = (float*)d_out;

    char* ws = (char*)d_ws;
    bf16*  Wb    = (bf16*)ws;                           // 256 KB
    bf16*  Kbuf  = (bf16*)(ws + (1 << 20));             // 2 MB
    bf16*  Vt    = (bf16*)(ws + (3 << 20));             // 2 MB
    bf16*  Opart = (bf16*)(ws + (5 << 20));             // 8 MB
    float* lpart = (float*)(ws + (13 << 20));           // 256 KB

    wconv_kernel<<<128, 256, 0, stream>>>(Wk, Wv, Wb);
    proj_kernel<<<512, 256, 0, stream>>>(x, Wb, Kbuf, Vt);
    attn_kernel<<<1024, 256, 0, stream>>>(Kbuf, Vt, Opart, lpart);
    attn_combine<<<1024, 256, 0, stream>>>(Opart, lpart, out);
}

// Round 7
// 127.756 us; speedup vs baseline: 1.9914x; 1.0189x over previous
//
#include <hip/hip_runtime.h>

// Head: k = x@Wk^T; q = k (source bug); wei = softmax(causal(q k^T / 8)); v = x@Wv^T; out = wei@v
// B=8, T=2048, C=1024, H=64. fp32 in/out, bf16 MFMA internally.
//
// R12 -> R13: Ps-swizzle/4-blocks-per-CU was null -> reverted to banked R7 attn.
// One lever: WORK-BALANCE remap in attn. Old: bid=(b,qb,c) with c fast -> same-CU
// blocks (spacing 256 under round-robin dispatch) share qb -> heaviest CU does 32
// block-iters vs avg 16.5 -> makespan 2x mean. New: c=bid>>8, u=bid&255, b=u>>5,
// qb0=u&31, qb = (c&1)? 31-qb0 : qb0 -> every CU-slot totals 16-17 block-iters.
// Bijective over (b,qb,c); outputs indexed by (b,qb,c) -> combine untouched,
// arithmetic bit-identical. proj frozen at HBM floor; ~90us harness fills fixed.

typedef __bf16 bf16;
typedef __bf16 bf16x4 __attribute__((ext_vector_type(4)));
typedef __bf16 bf16x8 __attribute__((ext_vector_type(8)));
typedef float  floatx4 __attribute__((ext_vector_type(4)));

#define T_LEN 2048
#define HEAD  64
#define CEMB  1024

static __device__ __forceinline__ bf16x8 cvt2(float4 a, float4 b) {
    bf16x8 r;
    r[0] = (bf16)a.x; r[1] = (bf16)a.y; r[2] = (bf16)a.z; r[3] = (bf16)a.w;
    r[4] = (bf16)b.x; r[5] = (bf16)b.y; r[6] = (bf16)b.z; r[7] = (bf16)b.w;
    return r;
}

// async 16B global->LDS. LDS dest is wave-uniform base + lane*16 (linear);
// global src is per-lane. Completion tracked by vmcnt; __syncthreads drains it.
static __device__ __forceinline__ void gload_lds16(const void* g, void* l) {
    __builtin_amdgcn_global_load_lds(
        (const __attribute__((address_space(1))) unsigned int*)(unsigned long long)g,
        (__attribute__((address_space(3))) unsigned int*)(unsigned long long)l,
        16, 0, 0);
}

// ---------------- Kernel 0: W fp32 -> bf16, [Wk;Wv] concat as Wb[128][1024]
__global__ __launch_bounds__(256) void wconv_kernel(const float* __restrict__ Wk,
                                                    const float* __restrict__ Wv,
                                                    bf16* __restrict__ Wb) {
    int i = (blockIdx.x * 256 + threadIdx.x) * 4;   // grid 128 covers 131072
    const float* src = (i < 64 * 1024) ? (Wk + i) : (Wv + (i - 64 * 1024));
    float4 f = *(const float4*)src;
    bf16x4 v;
    v[0] = (bf16)f.x; v[1] = (bf16)f.y; v[2] = (bf16)f.z; v[3] = (bf16)f.w;
    *(bf16x4*)&Wb[i] = v;
}

// ---------------- Kernel 1: projection GEMM. grid 512, tile 32 rows x 128 cols, BK=64.
// At its HBM roofline (~12us streaming the 64MB x): R7-banked structure, frozen.
__global__ __launch_bounds__(256) void proj_kernel(const float* __restrict__ x,
                                                   const bf16* __restrict__ Wb,
                                                   bf16* __restrict__ Kbuf,
                                                   bf16* __restrict__ Vt) {
    __shared__ __align__(16) bf16 As[2][32][72];
    __shared__ __align__(16) bf16 Bs[2][128][64];   // linear rows (128B), XOR-swizzled cols

    const int tid  = threadIdx.x;
    const int wave = tid >> 6;
    const int lane = tid & 63;
    const int quad = lane >> 4;
    const int low  = lane & 15;

    const long row0 = (long)blockIdx.x * 32;

    const int a_row = tid >> 3;          // 0..31, 8 fp32/thread
    const int a_col = (tid & 7) * 8;
    const float* abase = x + (row0 + a_row) * CEMB + a_col;

    // B staging geometry: linear LDS offset o=(r*256+tid)*16 -> row=r*32+(tid>>3),
    // col byte cbp=(tid&7)*16. Source col = cbp ^ ((row&7)<<4) (pre-swizzle).
    const int brow = tid >> 3;
    const int cbp  = (tid & 7) * 16;
    const int bsw  = cbp ^ ((brow & 7) << 4);
    const char* bsrc0 = (const char*)Wb + (long)brow * (CEMB * 2) + bsw;  // +r*65536 +s*128
    char* bdst = (char*)&Bs[0][0][0] + wave * 1024;                       // +nb*16384 +r*4096

    const int strip = wave & 1;          // 16-row M strip
    const int nhalf = wave >> 1;         // 0 -> K n-tiles, 1 -> V n-tiles
    const int nq    = nhalf * 4;

    floatx4 acc[4];
#pragma unroll
    for (int i = 0; i < 4; ++i) acc[i] = (floatx4){0.f, 0.f, 0.f, 0.f};

    float4 apf[2][2];

    // prologue: A step0 -> regs -> LDS0; B step0 DMA -> Bs[0]; A step1 -> regs
    apf[0][0] = ((const float4*)abase)[0];
    apf[0][1] = ((const float4*)abase)[1];
#pragma unroll
    for (int r = 0; r < 4; ++r)
        gload_lds16(bsrc0 + (long)r * 65536, bdst + r * 4096);
    *(bf16x8*)&As[0][a_row][a_col] = cvt2(apf[0][0], apf[0][1]);
    apf[1][0] = ((const float4*)(abase + 64))[0];
    apf[1][1] = ((const float4*)(abase + 64))[1];
    __syncthreads();   // drains B(0) DMA

    const int bswz = (low & 7) << 4;
    int buf = 0;
    for (int s = 0; s < 16; ++s) {
        if (s < 15) {
            const int q  = (s + 1) & 1;
            const int nb = buf ^ 1;
            // A(s+1) regs -> LDS[nb]; B(s+1) DMA -> Bs[nb] (in flight during compute)
            *(bf16x8*)&As[nb][a_row][a_col] = cvt2(apf[q][0], apf[q][1]);
#pragma unroll
            for (int r = 0; r < 4; ++r)
                gload_lds16(bsrc0 + (long)r * 65536 + (s + 1) * 128,
                            bdst + nb * 16384 + r * 4096);
        }
        if (s < 14) {   // A(s+2) global -> regs: full-iteration latency cover
            const int q  = s & 1;
            const int k0 = (s + 2) * 64;
            apf[q][0] = ((const float4*)(abase + k0))[0];
            apf[q][1] = ((const float4*)(abase + k0))[1];
        }
        // compute current step
        const char* bsl = (const char*)&Bs[buf][0][0];
#pragma unroll
        for (int ks = 0; ks < 2; ++ks) {
            bf16x8 afrag = *(const bf16x8*)&As[buf][strip * 16 + low][ks * 32 + quad * 8];
            const int cb = (ks * 64 + quad * 16) ^ bswz;
#pragma unroll
            for (int i = 0; i < 4; ++i) {
                bf16x8 bfrag = *(const bf16x8*)(bsl + ((nq + i) * 16 + low) * 128 + cb);
                acc[i] = __builtin_amdgcn_mfma_f32_16x16x32_bf16(afrag, bfrag, acc[i], 0, 0, 0);
            }
        }
        if (s < 15) {
            __syncthreads();
            buf ^= 1;
        }
    }

    // epilogue via LDS transpose (alias retired Bs): coalesced 16B stores.
    __syncthreads();
    bf16* Ek = (bf16*)&Bs[0][0][0];   // [32][72]: Ek[t][h]
    bf16* Ev = (bf16*)&Bs[1][0][0];   // [64][36]: Ev[h][t]
    if (nhalf == 0) {
#pragma unroll
        for (int i = 0; i < 4; ++i)
#pragma unroll
            for (int r = 0; r < 4; ++r)
                Ek[(strip * 16 + quad * 4 + r) * 72 + i * 16 + low] = (bf16)acc[i][r];
    } else {
#pragma unroll
        for (int i = 0; i < 4; ++i)
#pragma unroll
            for (int r = 0; r < 4; ++r)
                Ev[(i * 16 + low) * 36 + strip * 16 + quad * 4 + r] = (bf16)acc[i][r];
    }
    __syncthreads();

    const long bidx  = row0 >> 11;
    const int  tloc0 = (int)(row0 & 2047);
    {   // K copy: 16B contiguous, fully coalesced
        const int t  = tid >> 3;
        const int h0 = (tid & 7) * 8;
        *(bf16x8*)&Kbuf[(bidx * T_LEN + tloc0 + t) * HEAD + h0] = *(const bf16x8*)&Ek[t * 72 + h0];
    }
    {   // V copy: 16B contiguous per h-row
        const int h  = tid >> 2;
        const int t0 = (tid & 3) * 8;
        *(bf16x8*)&Vt[(bidx * HEAD + h) * T_LEN + tloc0 + t0] = *(const bf16x8*)&Ev[h * 36 + t0];
    }
}

// ---------------- Kernel 2: attention partial. q=k, causal, scale 1/8, fixed-max softmax.
// Work-balanced decode: c=bid>>8, u=bid&255, b=u>>5, qb0=u&31, qb=(c&1)?31-qb0:qb0.
// Chunk c: kv tiles j in {c, c+4, ...} <= qb (max 8 iters). Outputs at ((b*32+qb)*4+c).
// K/V staged via global_load_lds into swizzled Ks/Vs[2][64][64]; 1 barrier/iter.
__global__ __launch_bounds__(256) void attn_kernel(const bf16* __restrict__ Kbuf,
                                                   const bf16* __restrict__ Vt,
                                                   bf16* __restrict__ Opart,
                                                   float* __restrict__ lpart) {
    __shared__ __align__(16) bf16 Ks[2][64][64];
    __shared__ __align__(16) bf16 Vs[2][64][64];   // [h][kv]
    __shared__ __align__(16) bf16 Ps[4][16][72];   // per-wave private

    const int tid  = threadIdx.x;
    const int wave = tid >> 6;
    const int lane = tid & 63;
    const int quad = lane >> 4;
    const int low  = lane & 15;

    const int c   = blockIdx.x >> 8;         // 0..3
    const int u   = blockIdx.x & 255;
    const int b   = u >> 5;
    const int qb0 = u & 31;
    const int qb  = (c & 1) ? (31 - qb0) : qb0;
    const long opidx = ((long)(b * 32 + qb)) * 4 + c;

    const bf16* kbase = Kbuf + (long)b * T_LEN * HEAD;
    const bf16* vbase = Vt + (long)b * HEAD * T_LEN;

    // Q fragments (A-layout) direct from global (once per block)
    const bf16* qrow = kbase + (qb * 64 + wave * 16 + low) * HEAD + quad * 8;
    const bf16x8 qf0 = *(const bf16x8*)(qrow);
    const bf16x8 qf1 = *(const bf16x8*)(qrow + 32);

    bf16x8 ones;
#pragma unroll
    for (int i = 0; i < 8; ++i) ones[i] = (bf16)1.0f;

    floatx4 o[4], ol;
#pragma unroll
    for (int nt = 0; nt < 4; ++nt) o[nt] = (floatx4){0.f, 0.f, 0.f, 0.f};
    ol = (floatx4){0.f, 0.f, 0.f, 0.f};

    // staging geometry: linear o=(r*256+tid)*16 -> row=r*32+(tid>>3), cbp=(tid&7)*16.
    const int srow = tid >> 3;
    const int cbp  = (tid & 7) * 16;
    const int ssw  = cbp ^ ((srow & 7) << 4);
    const char* ksrc0 = (const char*)kbase + (long)srow * 128  + ssw;  // +j*8192 +r*4096
    const char* vsrc0 = (const char*)vbase + (long)srow * 4096 + ssw;  // +j*128  +r*131072
    char* kdst = (char*)&Ks[0][0][0] + wave * 1024;
    char* vdst = (char*)&Vs[0][0][0] + wave * 1024;

    const int sw  = (low & 7) << 4;
    const int cb0 = (quad * 16) ^ sw;
    const int cb1 = (64 + quad * 16) ^ sw;

    if (c <= qb) {
        // prologue: stage tile j=c into buf 0
#pragma unroll
        for (int r = 0; r < 2; ++r) {
            gload_lds16(ksrc0 + (long)c * 8192 + r * 4096, kdst + r * 4096);
            gload_lds16(vsrc0 + (long)c * 128 + (long)r * 131072, vdst + r * 4096);
        }
        __syncthreads();

        int buf = 0;
        for (int j = c; j <= qb; j += 4) {
            const bool more = (j + 4 <= qb);
            if (more) {   // DMA next tile into alternate buffer, in flight during compute
                const int nb = buf ^ 1;
#pragma unroll
                for (int r = 0; r < 2; ++r) {
                    gload_lds16(ksrc0 + (long)(j + 4) * 8192 + r * 4096,
                                kdst + nb * 8192 + r * 4096);
                    gload_lds16(vsrc0 + (long)(j + 4) * 128 + (long)r * 131072,
                                vdst + nb * 8192 + r * 4096);
                }
            }
            const char* ksl = (const char*)&Ks[buf][0][0];
            const char* vsl = (const char*)&Vs[buf][0][0];

            // S = Q K^T ; per-wave S tile [16 x 64]
            floatx4 s_[4];
#pragma unroll
            for (int nt = 0; nt < 4; ++nt) {
                bf16x8 kf0 = *(const bf16x8*)(ksl + (nt * 16 + low) * 128 + cb0);
                bf16x8 kf1 = *(const bf16x8*)(ksl + (nt * 16 + low) * 128 + cb1);
                floatx4 z = (floatx4){0.f, 0.f, 0.f, 0.f};
                z = __builtin_amdgcn_mfma_f32_16x16x32_bf16(qf0, kf0, z, 0, 0, 0);
                z = __builtin_amdgcn_mfma_f32_16x16x32_bf16(qf1, kf1, z, 0, 0, 0);
                s_[nt] = z;
            }

            // p = exp2(s * 0.125*log2e); causal mask on diagonal tile; P strip -> LDS
            const bool diag = (j == qb);
#pragma unroll
            for (int nt = 0; nt < 4; ++nt) {
#pragma unroll
                for (int r = 0; r < 4; ++r) {
                    float p = __builtin_amdgcn_exp2f(s_[nt][r] * 0.180336880f);
                    if (diag && (nt * 16 + low) > (wave * 16 + quad * 4 + r)) p = 0.f;
                    Ps[wave][quad * 4 + r][nt * 16 + low] = (bf16)p;
                }
            }

            // O += P V ; l += P . ones  (Ps wave-private: lgkmcnt ordering suffices)
            bf16x8 pf0 = *(const bf16x8*)&Ps[wave][low][quad * 8];
            bf16x8 pf1 = *(const bf16x8*)&Ps[wave][low][32 + quad * 8];
#pragma unroll
            for (int nt = 0; nt < 4; ++nt) {
                bf16x8 vf0 = *(const bf16x8*)(vsl + (nt * 16 + low) * 128 + cb0);
                bf16x8 vf1 = *(const bf16x8*)(vsl + (nt * 16 + low) * 128 + cb1);
                o[nt] = __builtin_amdgcn_mfma_f32_16x16x32_bf16(pf0, vf0, o[nt], 0, 0, 0);
                o[nt] = __builtin_amdgcn_mfma_f32_16x16x32_bf16(pf1, vf1, o[nt], 0, 0, 0);
            }
            ol = __builtin_amdgcn_mfma_f32_16x16x32_bf16(pf0, ones, ol, 0, 0, 0);
            ol = __builtin_amdgcn_mfma_f32_16x16x32_bf16(pf1, ones, ol, 0, 0, 0);

            if (more) {   // barrier drains the DMA; swap buffers
                __syncthreads();
                buf ^= 1;
            }
        }
    }

    // epilogue via LDS transpose (alias retired Ks, 16KB >= 9.2KB): coalesced stores
    __syncthreads();
    bf16* Eo = (bf16*)&Ks[0][0][0];   // [64][72]: Eo[row][h]
#pragma unroll
    for (int nt = 0; nt < 4; ++nt)
#pragma unroll
        for (int r = 0; r < 4; ++r)
            Eo[(wave * 16 + quad * 4 + r) * 72 + nt * 16 + low] = (bf16)o[nt][r];
    __syncthreads();
    {
        const int row  = tid >> 2;
        const int col0 = (tid & 3) * 16;
        bf16* ob = Opart + opidx * 4096 + row * 64 + col0;
        *(bf16x8*)(ob)     = *(const bf16x8*)&Eo[row * 72 + col0];
        *(bf16x8*)(ob + 8) = *(const bf16x8*)&Eo[row * 72 + col0 + 8];
    }
    if (low == 0) {
#pragma unroll
        for (int r = 0; r < 4; ++r)
            lpart[opidx * 64 + wave * 16 + quad * 4 + r] = ol[r];
    }
}

// ---------------- Kernel 3: combine 4 chunks. out = sum_c Opart / sum_c lpart.
// grid 1024: 4 blocks per (b,qb) tile (16 rows each) for occupancy.
__global__ __launch_bounds__(256) void attn_combine(const bf16* __restrict__ Opart,
                                                    const float* __restrict__ lpart,
                                                    float* __restrict__ out) {
    const int tile = blockIdx.x >> 2;        // 0..255 = b*32+qb
    const int rg   = blockIdx.x & 3;
    const int tid  = threadIdx.x;
    const int row  = rg * 16 + (tid >> 4);   // 0..63
    const int col0 = (tid & 15) * 4;

    const bf16*  ob = Opart + (long)tile * 4 * 4096 + row * 64 + col0;
    const float* lb = lpart + (long)tile * 4 * 64 + row;

    float l = lb[0] + lb[64] + lb[128] + lb[192];
    float rl = 1.0f / l;

    float s[4] = {0.f, 0.f, 0.f, 0.f};
#pragma unroll
    for (int ch = 0; ch < 4; ++ch) {
        bf16x4 u = *(const bf16x4*)(ob + ch * 4096);
#pragma unroll
        for (int i = 0; i < 4; ++i) s[i] += (float)u[i];
    }
    float4 w;
    w.x = s[0] * rl; w.y = s[1] * rl; w.z = s[2] * rl; w.w = s[3] * rl;
    *(float4*)(out + (long)tile * 4096 + row * 64 + col0) = w;
}

extern "C" void kernel_launch(void* const* d_in, const int* in_sizes, int n_in,
                              void* d_out, int out_size, void* d_ws, size_t ws_size,
                              hipStream_t stream) {
    const float* x  = (const float*)d_in[0];
    const float* Wk = (const float*)d_in[1];
    const float* Wv = (const float*)d_in[2];
    float* out = (float*)d_out;

    char* ws = (char*)d_ws;
    bf16*  Wb    = (bf16*)ws;                           // 256 KB
    bf16*  Kbuf  = (bf16*)(ws + (1 << 20));             // 2 MB
    bf16*  Vt    = (bf16*)(ws + (3 << 20));             // 2 MB
    bf16*  Opart = (bf16*)(ws + (5 << 20));             // 8 MB
    float* lpart = (float*)(ws + (13 << 20));           // 256 KB

    wconv_kernel<<<128, 256, 0, stream>>>(Wk, Wv, Wb);
    proj_kernel<<<512, 256, 0, stream>>>(x, Wb, Kbuf, Vt);
    attn_kernel<<<1024, 256, 0, stream>>>(Kbuf, Vt, Opart, lpart);
    attn_combine<<<1024, 256, 0, stream>>>(Opart, lpart, out);
}